// Round 5
// baseline (5279.358 us; speedup 1.0000x reference)
//
#include <hip/hip_runtime.h>

#define HD 768
#define G4 3072
#define T1 256
#define NS2 64
#define NL 3
#define NBLK_DIR 128   // blocks per direction in lstm_scan
#define UPB 6          // hidden units per block

__device__ __forceinline__ float sigf(float x) { return 1.0f / (1.0f + expf(-x)); }

__device__ __forceinline__ void fence_vm() {
    asm volatile("s_waitcnt vmcnt(0)" ::: "memory");
}

// ---------------------------------------------------------------------------
// Tiled f32 GEMM: C[m, jg] = sum_k A[m,k] * W[jg, k] (+ bias[jg])
// 64x64 tile, 256 threads, 4x4 acc (round-2 proven config).
// grid: (N/64, M/64).
// ---------------------------------------------------------------------------
__global__ __launch_bounds__(256) void gemm_f32(
    const float* __restrict__ A, int lda,
    const float* __restrict__ W, int ldw,
    const float* __restrict__ bias,
    float* __restrict__ C,
    int K, int n_per_chunk, long long chunk_stride)
{
    __shared__ __align__(16) float As[16 * 64];
    __shared__ __align__(16) float Ws[16 * 64];
    const int tid = threadIdx.x;
    const int tx = tid & 15, ty = tid >> 4;
    const int n0 = blockIdx.x * 64, m0 = blockIdx.y * 64;
    const int lr = tid >> 2, lc = tid & 3;

    float acc[4][4] = {{0.f}};
    const float* Ap = A + (size_t)(m0 + lr) * lda + lc * 4;
    const float* Wp = W + (size_t)(n0 + lr) * ldw + lc * 4;

    for (int k0 = 0; k0 < K; k0 += 16) {
        float4 av = *(const float4*)(Ap + k0);
        float4 wv = *(const float4*)(Wp + k0);
        __syncthreads();
        As[(lc * 4 + 0) * 64 + lr] = av.x;
        As[(lc * 4 + 1) * 64 + lr] = av.y;
        As[(lc * 4 + 2) * 64 + lr] = av.z;
        As[(lc * 4 + 3) * 64 + lr] = av.w;
        Ws[(lc * 4 + 0) * 64 + lr] = wv.x;
        Ws[(lc * 4 + 1) * 64 + lr] = wv.y;
        Ws[(lc * 4 + 2) * 64 + lr] = wv.z;
        Ws[(lc * 4 + 3) * 64 + lr] = wv.w;
        __syncthreads();
#pragma unroll
        for (int k = 0; k < 16; ++k) {
            float4 a = *(const float4*)&As[k * 64 + ty * 4];
            float4 b = *(const float4*)&Ws[k * 64 + tx * 4];
            float aa[4] = {a.x, a.y, a.z, a.w};
            float bb[4] = {b.x, b.y, b.z, b.w};
#pragma unroll
            for (int i = 0; i < 4; ++i)
#pragma unroll
                for (int j = 0; j < 4; ++j) acc[i][j] += aa[i] * bb[j];
        }
    }

    const int jg = n0 + tx * 4;
    const int chunk = jg / n_per_chunk;
    const int jo = jg - chunk * n_per_chunk;
    float4 bv = make_float4(0.f, 0.f, 0.f, 0.f);
    if (bias) bv = *(const float4*)&bias[jg];
    float* Cb = C + (size_t)chunk * chunk_stride + jo;
#pragma unroll
    for (int i = 0; i < 4; ++i) {
        const int m = m0 + ty * 4 + i;
        float4 o;
        o.x = acc[i][0] + bv.x;
        o.y = acc[i][1] + bv.y;
        o.z = acc[i][2] + bv.z;
        o.w = acc[i][3] + bv.w;
        *(float4*)&Cb[(size_t)m * n_per_chunk] = o;
    }
}

// ---------------------------------------------------------------------------
// Persistent bidirectional LSTM scan for one layer.
// grid 256 blocks: dir = bid&1, 128 blocks/dir, 6 units (x4 gates = 24 rows)
// per block, Whh rows in REGISTERS.
// Sync: NO barrier. Each block owns one 128-B line per (buf,dir):
//   hline[buf][dir][p][32 dwords]: dwords 0..23 = h (unit-major, batch inner),
//   dword 24 = tag (step number). Producer: store 24 dwords, vmcnt(0) drain
//   (wave 0), then store tag = s+1. Consumer: poll tag of its line (2 thr/line)
//   with relaxed agent load; tag>=s implies data is at LLC (drained before tag
//   was issued; atomic loads read the coherence point). Ping-pong bufs make
//   overwrite-before-read impossible. Tags monotonic; memset before each layer.
//   Whh: [2][3072][768]   G: [2][4][256][3072]   Hout: [4][256][1536]
// ---------------------------------------------------------------------------
__global__ __launch_bounds__(256) void lstm_scan(
    const float* __restrict__ Whh,
    const float* __restrict__ G,
    float* __restrict__ Hout,
    float* __restrict__ hline,
    int last)
{
    // padded LDS: unit k's 4 batch values in float4 slot 5*(k>>2)+(k&3)
    __shared__ __align__(16) float4 hs[960];
    __shared__ float gl[24 * 4];
    __shared__ float cst[24];
    const int tid = threadIdx.x;
    const int bid = blockIdx.x;
    const int dir = bid & 1;
    const int blkd = bid >> 1;
    const int u0 = blkd * UPB;

    const int ks = tid & 15, jp = tid >> 4;   // 16 k-slices x 16 row-pairs (12 used)
    const bool act = (jp < 12);
    const bool kz = act && (ks == 0);

    // consumer role: 2 threads per line
    const int cline = tid >> 1;               // 0..127
    const int chalf = tid & 1;

    // ---- load this block's Whh rows into registers (once per layer) ----
    const int r0 = 2 * jp, r1 = 2 * jp + 1;
    const int j0 = (r0 / 6) * HD + u0 + (r0 % 6);
    const int j1 = (r1 / 6) * HD + u0 + (r1 % 6);
    float4 w0[12], w1[12];
    if (act) {
        const float4* W4 = (const float4*)Whh + (size_t)dir * G4 * 192;
#pragma unroll
        for (int i = 0; i < 12; ++i) {
            w0[i] = W4[(size_t)j0 * 192 + i * 16 + ks];
            w1[i] = W4[(size_t)j1 * 192 + i * 16 + ks];
        }
    }
    if (tid < 24) cst[tid] = 0.f;

    const size_t gdb = (size_t)dir * 4 * T1 * G4;
    const size_t bstr = (size_t)T1 * G4;
    float* hsf = (float*)hs;

    // initial ih-gate prefetch for step 0
    float gA[4], gB[4];
    if (kz) {
        const int t0 = dir ? (T1 - 1) : 0;
        const float* Gt = G + gdb + (size_t)t0 * G4;
#pragma unroll
        for (int b = 0; b < 4; ++b) {
            gA[b] = Gt[(size_t)b * bstr + j0];
            gB[b] = Gt[(size_t)b * bstr + j1];
        }
    }

    for (int s = 0; s < T1; ++s) {
        const int t = dir ? (T1 - 1 - s) : s;

        // ---- stage h_t into LDS (poll tag of own line, then load 12 dwords) ----
        if (s == 0) {
#pragma unroll
            for (int r = 0; r < 3; ++r) {
                const int k = tid + 256 * r;
                hs[5 * (k >> 2) + (k & 3)] = make_float4(0.f, 0.f, 0.f, 0.f);
            }
        } else {
            const float* base =
                hline + (((size_t)((s & 1) * 2 + dir)) * 128 + cline) * 32;
            const unsigned* tagp = (const unsigned*)(base + 24);
            while (__hip_atomic_load(tagp, __ATOMIC_RELAXED,
                                     __HIP_MEMORY_SCOPE_AGENT) < (unsigned)s) {}
#pragma unroll
            for (int j = 0; j < 12; ++j) {
                const int d = chalf * 12 + j;
                const float v = __hip_atomic_load(base + d, __ATOMIC_RELAXED,
                                                  __HIP_MEMORY_SCOPE_AGENT);
                const int k = cline * 6 + (d >> 2);
                hsf[(5 * (k >> 2) + (k & 3)) * 4 + (d & 3)] = v;
            }
        }
        __syncthreads();

        // ---- matvec: 2 rows x 48 k x 4 batch per thread ----
        if (act) {
            float4 a0 = make_float4(0.f, 0.f, 0.f, 0.f);
            float4 a1 = make_float4(0.f, 0.f, 0.f, 0.f);
#pragma unroll
            for (int i = 0; i < 12; ++i) {
                const int pb = 5 * (i * 16 + ks);
                const float4 h0 = hs[pb + 0];
                const float4 h1 = hs[pb + 1];
                const float4 h2 = hs[pb + 2];
                const float4 h3 = hs[pb + 3];
                const float4 wa = w0[i];
                const float4 wb = w1[i];
                a0.x += wa.x * h0.x; a0.y += wa.x * h0.y; a0.z += wa.x * h0.z; a0.w += wa.x * h0.w;
                a0.x += wa.y * h1.x; a0.y += wa.y * h1.y; a0.z += wa.y * h1.z; a0.w += wa.y * h1.w;
                a0.x += wa.z * h2.x; a0.y += wa.z * h2.y; a0.z += wa.z * h2.z; a0.w += wa.z * h2.w;
                a0.x += wa.w * h3.x; a0.y += wa.w * h3.y; a0.z += wa.w * h3.z; a0.w += wa.w * h3.w;
                a1.x += wb.x * h0.x; a1.y += wb.x * h0.y; a1.z += wb.x * h0.z; a1.w += wb.x * h0.w;
                a1.x += wb.y * h1.x; a1.y += wb.y * h1.y; a1.z += wb.y * h1.z; a1.w += wb.y * h1.w;
                a1.x += wb.z * h2.x; a1.y += wb.z * h2.y; a1.z += wb.z * h2.z; a1.w += wb.z * h2.w;
                a1.x += wb.w * h3.x; a1.y += wb.w * h3.y; a1.z += wb.w * h3.z; a1.w += wb.w * h3.w;
            }
#pragma unroll
            for (int off = 8; off; off >>= 1) {
                a0.x += __shfl_xor(a0.x, off);
                a0.y += __shfl_xor(a0.y, off);
                a0.z += __shfl_xor(a0.z, off);
                a0.w += __shfl_xor(a0.w, off);
                a1.x += __shfl_xor(a1.x, off);
                a1.y += __shfl_xor(a1.y, off);
                a1.z += __shfl_xor(a1.z, off);
                a1.w += __shfl_xor(a1.w, off);
            }
            if (ks == 0) {
                gl[r0 * 4 + 0] = a0.x + gA[0];
                gl[r0 * 4 + 1] = a0.y + gA[1];
                gl[r0 * 4 + 2] = a0.z + gA[2];
                gl[r0 * 4 + 3] = a0.w + gA[3];
                gl[r1 * 4 + 0] = a1.x + gB[0];
                gl[r1 * 4 + 1] = a1.y + gB[1];
                gl[r1 * 4 + 2] = a1.z + gB[2];
                gl[r1 * 4 + 3] = a1.w + gB[3];
            }
        }
        __syncthreads();

        // ---- cell update: 6 units x 4 batch; publish into own line ----
        float hval = 0.f;
        float* wline =
            hline + (((size_t)(((s + 1) & 1) * 2 + dir)) * 128 + blkd) * 32;
        if (tid < 24) {
            const int ui = tid >> 2, b = tid & 3;
            const float gi = gl[(0 * 6 + ui) * 4 + b];
            const float gf = gl[(1 * 6 + ui) * 4 + b];
            const float gg = gl[(2 * 6 + ui) * 4 + b];
            const float go = gl[(3 * 6 + ui) * 4 + b];
            const float c = sigf(gf) * cst[tid] + sigf(gi) * tanhf(gg);
            hval = sigf(go) * tanhf(c);
            cst[tid] = c;
            if (s < T1 - 1) {
                // line dword = unit_local*4 + b == tid
                __hip_atomic_store(wline + tid, hval, __ATOMIC_RELAXED,
                                   __HIP_MEMORY_SCOPE_AGENT);
            }
        }
        if (s < T1 - 1) {
            if (tid < 64) fence_vm();   // wave 0: all 24 h stores at LLC
            if (tid == 0) {
                __hip_atomic_store((unsigned*)(wline + 24), (unsigned)(s + 1),
                                   __ATOMIC_RELAXED, __HIP_MEMORY_SCOPE_AGENT);
            }
        }
        // Hout (HBM) after publication: off the critical path
        if (tid < 24) {
            const int ui = tid >> 2, b = tid & 3;
            Hout[((size_t)b * T1 + t) * (2 * HD) + dir * HD + (u0 + ui)] =
                last ? tanhf(hval) : hval;
        }
        // prefetch next step's ih gates; in flight while others publish/poll
        if (s < T1 - 1 && kz) {
            const int tn = dir ? (T1 - 2 - s) : (s + 1);
            const float* Gt = G + gdb + (size_t)tn * G4;
#pragma unroll
            for (int b = 0; b < 4; ++b) {
                gA[b] = Gt[(size_t)b * bstr + j0];
                gB[b] = Gt[(size_t)b * bstr + j1];
            }
        }
    }
}

// ---------------------------------------------------------------------------
// Attention: per (b,q) block. hq includes attn_b1. hk: [4*256][768].
// ---------------------------------------------------------------------------
__global__ __launch_bounds__(256) void attn_kernel(
    const float* __restrict__ hq,
    const float* __restrict__ hk,
    const float* __restrict__ w2p,
    const float* __restrict__ b2p,
    const float* __restrict__ am,
    const float* __restrict__ sm,
    const float* __restrict__ H3,
    float* __restrict__ sf)
{
    __shared__ float hql[HD];
    __shared__ float w2[HD];
    __shared__ float Ash[T1];
    __shared__ float red[1];
    const int tid = threadIdx.x;
    const int bq = blockIdx.x;
    const int b = bq >> 6;

    for (int e = tid; e < HD; e += 256) {
        hql[e] = hq[(size_t)bq * HD + e];
        w2[e] = w2p[e];
    }
    __syncthreads();

    const int lane = tid & 63, wid = tid >> 6;
    const float amv = am[bq];
    const float b2 = b2p[0];
    for (int k = wid; k < T1; k += 4) {
        const float* hkp = hk + ((size_t)b * T1 + k) * HD;
        float s = 0.f;
#pragma unroll
        for (int i = 0; i < 12; ++i) {
            const int e = i * 64 + lane;
            float v = hql[e] + hkp[e];
            v = v > 0.f ? v : 0.f;
            s += v * w2[e];
        }
#pragma unroll
        for (int off = 32; off; off >>= 1) s += __shfl_xor(s, off);
        if (lane == 0) {
            const float m = amv * sm[b * T1 + k];
            Ash[k] = (m == 0.f) ? 0.f : expf(s + b2);
        }
    }
    __syncthreads();

    if (tid < 64) {
        float p = Ash[tid] + Ash[tid + 64] + Ash[tid + 128] + Ash[tid + 192];
#pragma unroll
        for (int off = 32; off; off >>= 1) p += __shfl_xor(p, off);
        if (tid == 0) red[0] = fmaxf(p, 2e-15f);
    }
    __syncthreads();
    const float inv = 1.f / red[0];

    for (int d = tid; d < 2 * HD; d += 256) {
        const float* hp = H3 + (size_t)b * T1 * 2 * HD + d;
        float acc = 0.f;
        for (int k = 0; k < T1; ++k) acc += Ash[k] * hp[(size_t)k * 2 * HD];
        sf[(size_t)bq * 2 * HD + d] = acc * inv;
    }
}

// state_semantic + val. grid 4, block 256.
__global__ __launch_bounds__(256) void val_kernel(
    const float* __restrict__ sf, const float* __restrict__ am,
    const float* __restrict__ vw, const float* __restrict__ vb,
    float* __restrict__ val)
{
    __shared__ float red[4];
    const int b = blockIdx.x, tid = threadIdx.x;
    float num = 0.f;
    for (int q = 0; q < NS2; ++q) num += am[b * NS2 + q];
    float acc = 0.f;
    for (int d = tid; d < 2 * HD; d += 256) {
        float s = 0.f;
        for (int q = 0; q < NS2; ++q) s += sf[((size_t)(b * NS2 + q)) * 2 * HD + d];
        acc += (s / num) * vw[d];
    }
#pragma unroll
    for (int off = 32; off; off >>= 1) acc += __shfl_xor(acc, off);
    if ((tid & 63) == 0) red[tid >> 6] = acc;
    __syncthreads();
    if (tid == 0) val[b] = red[0] + red[1] + red[2] + red[3] + vb[0];
}

// adv dot + mean-subtract + output. grid 4, block 256.
__global__ __launch_bounds__(256) void final_kernel(
    const float* __restrict__ Tb,   // [3][256][768]
    const float* __restrict__ act,  // [4][64][768]
    const float* __restrict__ bias, // [3]
    const float* __restrict__ val,  // [4]
    float* __restrict__ out)        // [256][3]
{
    __shared__ float adv[192];
    __shared__ float red[4];
    const int b = blockIdx.x, tid = threadIdx.x;
    const int lane = tid & 63, wid = tid >> 6;

    for (int idx = wid; idx < 192; idx += 4) {
        const int q = idx / 3, l = idx - q * 3;
        const float* tp = Tb + (size_t)l * T1 * HD + (size_t)(b * NS2 + q) * HD;
        const float* ap = act + (size_t)(b * NS2 + q) * HD;
        float s = 0.f;
#pragma unroll
        for (int i = 0; i < 12; ++i) {
            const int h = i * 64 + lane;
            s += tp[h] * ap[h];
        }
#pragma unroll
        for (int off = 32; off; off >>= 1) s += __shfl_xor(s, off);
        if (lane == 0) adv[idx] = s + bias[l];
    }
    __syncthreads();
    float part = (tid < 192) ? adv[tid] : 0.f;
#pragma unroll
    for (int off = 32; off; off >>= 1) part += __shfl_xor(part, off);
    if (lane == 0) red[wid] = part;
    __syncthreads();
    const float mean = (red[0] + red[1] + red[2] + red[3]) * (1.f / 192.f);
    const float vv = val[b];
    for (int idx = tid; idx < 192; idx += 256) {
        const int q = idx / 3, l = idx - q * 3;
        out[(size_t)(b * NS2 + q) * NL + l] = vv + adv[idx] - mean;
    }
}

// ---------------------------------------------------------------------------
extern "C" void kernel_launch(void* const* d_in, const int* in_sizes, int n_in,
                              void* d_out, int out_size, void* d_ws, size_t ws_size,
                              hipStream_t stream)
{
    const float* states = (const float*)d_in[0];
    const float* state_mask = (const float*)d_in[1];
    const float* actions = (const float*)d_in[2];
    const float* actions_mask = (const float*)d_in[3];
    const float* Wih0 = (const float*)d_in[4];   // [2,3072,768]
    const float* Whh0 = (const float*)d_in[5];   // [2,3072,768]
    const float* b0 = (const float*)d_in[6];     // [2,3072]
    const float* Wih12 = (const float*)d_in[7];  // [2,2,3072,1536]
    const float* Whh12 = (const float*)d_in[8];  // [2,2,3072,768]
    const float* b12 = (const float*)d_in[9];    // [2,2,3072]
    const float* aW1 = (const float*)d_in[10];   // [768,2304]
    const float* ab1 = (const float*)d_in[11];   // [768]
    const float* aW2 = (const float*)d_in[12];   // [1,768]
    const float* ab2 = (const float*)d_in[13];   // [1]
    const float* vW = (const float*)d_in[14];    // [1,1536]
    const float* vb = (const float*)d_in[15];    // [1]
    const float* wgt = (const float*)d_in[16];   // [3,768,1536]
    const float* bias = (const float*)d_in[17];  // [3]
    float* out = (float*)d_out;

    float* ws = (float*)d_ws;
    float* G = ws;                        // [2][4][256][3072] = 6291456 floats
    float* B1 = G + 6291456;              // H1, later H3  (1572864)
    float* B2 = B1 + 1572864;             // H2            (1572864)
    float* hline = B2 + 1572864;          // [2][2][128][32] = 16384 floats
    // after LSTM phase, G region is reused for attention temporaries:
    float* hq = G;                        // 256*768   = 196608
    float* hkb = G + 196608;              // 1024*768  = 786432
    float* sf = G + 983040;               // 256*1536  = 393216
    float* Tb = G + 1376256;              // 3*256*768 = 589824
    float* val = G + 1966080;             // 4

    const dim3 blk(256);
    const long long gstride = (long long)4 * T1 * G4;  // per-direction chunk in G

    // ---------------- layer 0 ----------------
    hipMemsetAsync(hline, 0, 65536, stream);
    gemm_f32<<<dim3(6144 / 64, 1024 / 64), blk, 0, stream>>>(
        states, HD, Wih0, HD, b0, G, HD, G4, gstride);
    lstm_scan<<<dim3(256), blk, 0, stream>>>(Whh0, G, B1, hline, 0);
    // ---------------- layer 1 ----------------
    hipMemsetAsync(hline, 0, 65536, stream);
    gemm_f32<<<dim3(6144 / 64, 1024 / 64), blk, 0, stream>>>(
        B1, 2 * HD, Wih12, 2 * HD, b12, G, 2 * HD, G4, gstride);
    lstm_scan<<<dim3(256), blk, 0, stream>>>(Whh12, G, B2, hline, 0);
    // ---------------- layer 2 ----------------
    hipMemsetAsync(hline, 0, 65536, stream);
    gemm_f32<<<dim3(6144 / 64, 1024 / 64), blk, 0, stream>>>(
        B2, 2 * HD, Wih12 + (size_t)6144 * 1536, 2 * HD, b12 + 6144, G, 2 * HD, G4, gstride);
    lstm_scan<<<dim3(256), blk, 0, stream>>>(
        Whh12 + (size_t)2 * G4 * HD, G, B1, hline, 1);
    // ---------------- attention ----------------
    // hq = actions @ W1q^T + b1   (W1q = aW1[:, :768], row stride 2304)
    gemm_f32<<<dim3(768 / 64, 256 / 64), blk, 0, stream>>>(
        actions, HD, aW1, 2304, ab1, hq, HD, HD, 0);
    // hk = out @ W1k^T            (W1k = aW1[:, 768:2304], K = 1536)
    gemm_f32<<<dim3(768 / 64, 1024 / 64), blk, 0, stream>>>(
        B1, 2 * HD, aW1 + 768, 2304, nullptr, hkb, 2 * HD, HD, 0);
    attn_kernel<<<dim3(256), blk, 0, stream>>>(hq, hkb, aW2, ab2, actions_mask,
                                               state_mask, B1, sf);
    val_kernel<<<dim3(4), blk, 0, stream>>>(sf, actions_mask, vW, vb, val);
    // T_l = sf @ weight[l]^T
    for (int l = 0; l < NL; ++l) {
        gemm_f32<<<dim3(768 / 64, 256 / 64), blk, 0, stream>>>(
            sf, 2 * HD, wgt + (size_t)l * HD * 2 * HD, 2 * HD, nullptr,
            Tb + (size_t)l * T1 * HD, 2 * HD, HD, 0);
    }
    final_kernel<<<dim3(4), blk, 0, stream>>>(Tb, actions, bias, val, out);
}

// Round 6
// 4295.736 us; speedup vs baseline: 1.2290x; 1.2290x over previous
//
#include <hip/hip_runtime.h>

#define HD 768
#define G4 3072
#define T1 256
#define NS2 64
#define NL 3
#define NBLK_DIR 128   // blocks per direction in lstm_scan
#define UPB 6          // hidden units per block

__device__ __forceinline__ float sigf(float x) { return 1.0f / (1.0f + expf(-x)); }

__device__ __forceinline__ void fence_vm() {
    asm volatile("s_waitcnt vmcnt(0)" ::: "memory");
}

// ---------------------------------------------------------------------------
// Tiled f32 GEMM: C[m, jg] = sum_k A[m,k] * W[jg, k] (+ bias[jg])
// 64x64 tile, 256 threads, 4x4 acc, double-buffered LDS (1 barrier/K-tile,
// global prefetch overlaps compute). grid: (N/64, M/64).
// ---------------------------------------------------------------------------
__global__ __launch_bounds__(256) void gemm_f32(
    const float* __restrict__ A, int lda,
    const float* __restrict__ W, int ldw,
    const float* __restrict__ bias,
    float* __restrict__ C,
    int K, int n_per_chunk, long long chunk_stride)
{
    __shared__ __align__(16) float As[2][16 * 64];
    __shared__ __align__(16) float Ws[2][16 * 64];
    const int tid = threadIdx.x;
    const int tx = tid & 15, ty = tid >> 4;
    const int n0 = blockIdx.x * 64, m0 = blockIdx.y * 64;
    const int lr = tid >> 2, lc = tid & 3;

    float acc[4][4] = {{0.f}};
    const float* Ap = A + (size_t)(m0 + lr) * lda + lc * 4;
    const float* Wp = W + (size_t)(n0 + lr) * ldw + lc * 4;

    float4 av = *(const float4*)(Ap);
    float4 wv = *(const float4*)(Wp);
    int cur = 0;
    for (int k0 = 0; k0 < K; k0 += 16) {
        float* Asb = As[cur];
        float* Wsb = Ws[cur];
        Asb[(lc * 4 + 0) * 64 + lr] = av.x;
        Asb[(lc * 4 + 1) * 64 + lr] = av.y;
        Asb[(lc * 4 + 2) * 64 + lr] = av.z;
        Asb[(lc * 4 + 3) * 64 + lr] = av.w;
        Wsb[(lc * 4 + 0) * 64 + lr] = wv.x;
        Wsb[(lc * 4 + 1) * 64 + lr] = wv.y;
        Wsb[(lc * 4 + 2) * 64 + lr] = wv.z;
        Wsb[(lc * 4 + 3) * 64 + lr] = wv.w;
        __syncthreads();
        if (k0 + 16 < K) {
            av = *(const float4*)(Ap + k0 + 16);
            wv = *(const float4*)(Wp + k0 + 16);
        }
#pragma unroll
        for (int k = 0; k < 16; ++k) {
            float4 a = *(const float4*)&Asb[k * 64 + ty * 4];
            float4 b = *(const float4*)&Wsb[k * 64 + tx * 4];
            float aa[4] = {a.x, a.y, a.z, a.w};
            float bb[4] = {b.x, b.y, b.z, b.w};
#pragma unroll
            for (int i = 0; i < 4; ++i)
#pragma unroll
                for (int j = 0; j < 4; ++j) acc[i][j] += aa[i] * bb[j];
        }
        cur ^= 1;
    }

    const int jg = n0 + tx * 4;
    const int chunk = jg / n_per_chunk;
    const int jo = jg - chunk * n_per_chunk;
    float4 bv = make_float4(0.f, 0.f, 0.f, 0.f);
    if (bias) bv = *(const float4*)&bias[jg];
    float* Cb = C + (size_t)chunk * chunk_stride + jo;
#pragma unroll
    for (int i = 0; i < 4; ++i) {
        const int m = m0 + ty * 4 + i;
        float4 o;
        o.x = acc[i][0] + bv.x;
        o.y = acc[i][1] + bv.y;
        o.z = acc[i][2] + bv.z;
        o.w = acc[i][3] + bv.w;
        *(float4*)&Cb[(size_t)m * n_per_chunk] = o;
    }
}

// ---------------------------------------------------------------------------
// Persistent bidirectional LSTM scan for one layer (round-2 protocol).
// grid 256 blocks: dir = bid&1, 128 blocks/dir, 6 units (x4 gates = 24 rows)
// per block. Whh rows in REGISTERS. Relaxed striped-counter barrier, master
// block polls 8 stripes, publishes gen; others spin on gen. h exchange via
// agent-scope relaxed atomics. Counters zeroed before each layer.
// Deltas vs round 2 (publisher chain only): Hout store AFTER fence+arrival;
// no pre-arrival __syncthreads.
//   Whh: [2][3072][768]   G: [2][4][256][3072]
//   Hout: [4][256][1536]  hglob: [2 buf][2 dir][768][4]  (unit-major, batch inner)
//   bar: ctr[dir][8] at bar + dir*256 + i*32 ; gen[dir] at bar + 512 + dir*32
// ---------------------------------------------------------------------------
__global__ __launch_bounds__(256) void lstm_scan(
    const float* __restrict__ Whh,
    const float* __restrict__ G,
    float* __restrict__ Hout,
    float* __restrict__ hglob,
    unsigned* __restrict__ bar,
    int last)
{
    // padded LDS: unit k's 4 batch values in float4 slot 5*(k>>2)+(k&3)
    __shared__ __align__(16) float4 hs[960];
    __shared__ float gl[24 * 4];
    __shared__ float cst[24];
    const int tid = threadIdx.x;
    const int bid = blockIdx.x;
    const int dir = bid & 1;
    const int blkd = bid >> 1;
    const int u0 = blkd * UPB;

    const int ks = tid & 15, jp = tid >> 4;   // 16 k-slices x 16 row-pairs (12 used)
    const bool act = (jp < 12);
    const bool kz = act && (ks == 0);

    // ---- load this block's Whh rows into registers (once per layer) ----
    const int r0 = 2 * jp, r1 = 2 * jp + 1;
    const int j0 = (r0 / 6) * HD + u0 + (r0 % 6);
    const int j1 = (r1 / 6) * HD + u0 + (r1 % 6);
    float4 w0[12], w1[12];
    if (act) {
        const float4* W4 = (const float4*)Whh + (size_t)dir * G4 * 192;
#pragma unroll
        for (int i = 0; i < 12; ++i) {
            w0[i] = W4[(size_t)j0 * 192 + i * 16 + ks];
            w1[i] = W4[(size_t)j1 * 192 + i * 16 + ks];
        }
    }
    if (tid < 24) cst[tid] = 0.f;

    unsigned* ctr = bar + dir * 256;
    unsigned* genp = bar + 512 + dir * 32;
    const size_t gdb = (size_t)dir * 4 * T1 * G4;
    const size_t bstr = (size_t)T1 * G4;
    float* hsf = (float*)hs;

    for (int s = 0; s < T1; ++s) {
        const int t = dir ? (T1 - 1 - s) : s;

        // prefetch ih-gate values (independent of h; hides under staging/matvec)
        float gA[4], gB[4];
        if (kz) {
            const float* Gt = G + gdb + (size_t)t * G4;
#pragma unroll
            for (int b = 0; b < 4; ++b) {
                gA[b] = Gt[(size_t)b * bstr + j0];
                gB[b] = Gt[(size_t)b * bstr + j1];
            }
        }

        // ---- stage h_t into LDS ----
        if (s == 0) {
#pragma unroll
            for (int r = 0; r < 3; ++r) {
                const int k = tid + 256 * r;
                hs[5 * (k >> 2) + (k & 3)] = make_float4(0.f, 0.f, 0.f, 0.f);
            }
        } else {
            const float* hp = hglob + ((size_t)((s & 1) * 2 + dir)) * HD * 4;
            float hv[12];
#pragma unroll
            for (int r = 0; r < 12; ++r)
                hv[r] = __hip_atomic_load(hp + tid + 256 * r, __ATOMIC_RELAXED,
                                          __HIP_MEMORY_SCOPE_AGENT);
#pragma unroll
            for (int r = 0; r < 12; ++r) {
                const int i = tid + 256 * r;
                const int k = i >> 2, b = i & 3;
                hsf[(5 * (k >> 2) + (k & 3)) * 4 + b] = hv[r];
            }
        }
        __syncthreads();

        // ---- matvec: 2 rows x 48 k x 4 batch per thread ----
        if (act) {
            float4 a0 = make_float4(0.f, 0.f, 0.f, 0.f);
            float4 a1 = make_float4(0.f, 0.f, 0.f, 0.f);
#pragma unroll
            for (int i = 0; i < 12; ++i) {
                const int pb = 5 * (i * 16 + ks);
                const float4 h0 = hs[pb + 0];
                const float4 h1 = hs[pb + 1];
                const float4 h2 = hs[pb + 2];
                const float4 h3 = hs[pb + 3];
                const float4 wa = w0[i];
                const float4 wb = w1[i];
                a0.x += wa.x * h0.x; a0.y += wa.x * h0.y; a0.z += wa.x * h0.z; a0.w += wa.x * h0.w;
                a0.x += wa.y * h1.x; a0.y += wa.y * h1.y; a0.z += wa.y * h1.z; a0.w += wa.y * h1.w;
                a0.x += wa.z * h2.x; a0.y += wa.z * h2.y; a0.z += wa.z * h2.z; a0.w += wa.z * h2.w;
                a0.x += wa.w * h3.x; a0.y += wa.w * h3.y; a0.z += wa.w * h3.z; a0.w += wa.w * h3.w;
                a1.x += wb.x * h0.x; a1.y += wb.x * h0.y; a1.z += wb.x * h0.z; a1.w += wb.x * h0.w;
                a1.x += wb.y * h1.x; a1.y += wb.y * h1.y; a1.z += wb.y * h1.z; a1.w += wb.y * h1.w;
                a1.x += wb.z * h2.x; a1.y += wb.z * h2.y; a1.z += wb.z * h2.z; a1.w += wb.z * h2.w;
                a1.x += wb.w * h3.x; a1.y += wb.w * h3.y; a1.z += wb.w * h3.z; a1.w += wb.w * h3.w;
            }
#pragma unroll
            for (int off = 8; off; off <<= 1) {
                a0.x += __shfl_xor(a0.x, off);
                a0.y += __shfl_xor(a0.y, off);
                a0.z += __shfl_xor(a0.z, off);
                a0.w += __shfl_xor(a0.w, off);
                a1.x += __shfl_xor(a1.x, off);
                a1.y += __shfl_xor(a1.y, off);
                a1.z += __shfl_xor(a1.z, off);
                a1.w += __shfl_xor(a1.w, off);
                if (off == 8) break;   // single step needed? no: keep full tree below
            }
            // full 16-lane butterfly (offsets 1,2,4,8)
#pragma unroll
            for (int off = 1; off < 8; off <<= 1) {
                a0.x += __shfl_xor(a0.x, off);
                a0.y += __shfl_xor(a0.y, off);
                a0.z += __shfl_xor(a0.z, off);
                a0.w += __shfl_xor(a0.w, off);
                a1.x += __shfl_xor(a1.x, off);
                a1.y += __shfl_xor(a1.y, off);
                a1.z += __shfl_xor(a1.z, off);
                a1.w += __shfl_xor(a1.w, off);
            }
            if (ks == 0) {
                gl[r0 * 4 + 0] = a0.x + gA[0];
                gl[r0 * 4 + 1] = a0.y + gA[1];
                gl[r0 * 4 + 2] = a0.z + gA[2];
                gl[r0 * 4 + 3] = a0.w + gA[3];
                gl[r1 * 4 + 0] = a1.x + gB[0];
                gl[r1 * 4 + 1] = a1.y + gB[1];
                gl[r1 * 4 + 2] = a1.z + gB[2];
                gl[r1 * 4 + 3] = a1.w + gB[3];
            }
        }
        __syncthreads();

        // ---- cell update: 6 units x 4 batch; publish h at agent scope ----
        float hval = 0.f;
        if (tid < 24) {
            const int ui = tid >> 2, b = tid & 3;
            const float gi = gl[(0 * 6 + ui) * 4 + b];
            const float gf = gl[(1 * 6 + ui) * 4 + b];
            const float gg = gl[(2 * 6 + ui) * 4 + b];
            const float go = gl[(3 * 6 + ui) * 4 + b];
            const float c = sigf(gf) * cst[tid] + sigf(gi) * tanhf(gg);
            hval = sigf(go) * tanhf(c);
            cst[tid] = c;
            __hip_atomic_store(
                &hglob[(((size_t)(((s + 1) & 1) * 2 + dir)) * HD + (u0 + ui)) * 4 + b],
                hval, __ATOMIC_RELAXED, __HIP_MEMORY_SCOPE_AGENT);
        }
        // wave 0 drains its h stores, then thread 0 announces arrival
        if (tid < 64) fence_vm();
        if (s < T1 - 1 && tid == 0) {
            __hip_atomic_fetch_add(&ctr[(blkd & 7) * 32], 1u, __ATOMIC_RELAXED,
                                   __HIP_MEMORY_SCOPE_AGENT);
        }
        // Hout store (HBM) AFTER the fence+arrival: off the publisher chain
        if (tid < 24) {
            const int ui = tid >> 2, b = tid & 3;
            Hout[((size_t)b * T1 + t) * (2 * HD) + dir * HD + (u0 + ui)] =
                last ? tanhf(hval) : hval;
        }

        // ---- wait: master polls stripes, publishes gen; others spin ----
        if (s < T1 - 1) {
            if (tid == 0) {
                const unsigned tgt = (unsigned)(NBLK_DIR * (s + 1));
                if (blkd == 0) {
                    for (;;) {
                        unsigned sum = 0;
#pragma unroll
                        for (int i = 0; i < 8; ++i)
                            sum += __hip_atomic_load(&ctr[i * 32], __ATOMIC_RELAXED,
                                                     __HIP_MEMORY_SCOPE_AGENT);
                        if (sum >= tgt) break;
                    }
                    __hip_atomic_store(genp, (unsigned)(s + 1), __ATOMIC_RELAXED,
                                       __HIP_MEMORY_SCOPE_AGENT);
                } else {
                    while (__hip_atomic_load(genp, __ATOMIC_RELAXED,
                                             __HIP_MEMORY_SCOPE_AGENT) <
                           (unsigned)(s + 1)) {}
                }
            }
            __syncthreads();
        }
    }
}

// ---------------------------------------------------------------------------
// Attention: per (b,q) block. hq includes attn_b1. hk: [4*256][768].
// ---------------------------------------------------------------------------
__global__ __launch_bounds__(256) void attn_kernel(
    const float* __restrict__ hq,
    const float* __restrict__ hk,
    const float* __restrict__ w2p,
    const float* __restrict__ b2p,
    const float* __restrict__ am,
    const float* __restrict__ sm,
    const float* __restrict__ H3,
    float* __restrict__ sf)
{
    __shared__ float hql[HD];
    __shared__ float w2[HD];
    __shared__ float Ash[T1];
    __shared__ float red[1];
    const int tid = threadIdx.x;
    const int bq = blockIdx.x;
    const int b = bq >> 6;

    for (int e = tid; e < HD; e += 256) {
        hql[e] = hq[(size_t)bq * HD + e];
        w2[e] = w2p[e];
    }
    __syncthreads();

    const int lane = tid & 63, wid = tid >> 6;
    const float amv = am[bq];
    const float b2 = b2p[0];
    for (int k = wid; k < T1; k += 4) {
        const float* hkp = hk + ((size_t)b * T1 + k) * HD;
        float s = 0.f;
#pragma unroll
        for (int i = 0; i < 12; ++i) {
            const int e = i * 64 + lane;
            float v = hql[e] + hkp[e];
            v = v > 0.f ? v : 0.f;
            s += v * w2[e];
        }
#pragma unroll
        for (int off = 32; off; off >>= 1) s += __shfl_xor(s, off);
        if (lane == 0) {
            const float m = amv * sm[b * T1 + k];
            Ash[k] = (m == 0.f) ? 0.f : expf(s + b2);
        }
    }
    __syncthreads();

    if (tid < 64) {
        float p = Ash[tid] + Ash[tid + 64] + Ash[tid + 128] + Ash[tid + 192];
#pragma unroll
        for (int off = 32; off; off >>= 1) p += __shfl_xor(p, off);
        if (tid == 0) red[0] = fmaxf(p, 2e-15f);
    }
    __syncthreads();
    const float inv = 1.f / red[0];

    for (int d = tid; d < 2 * HD; d += 256) {
        const float* hp = H3 + (size_t)b * T1 * 2 * HD + d;
        float acc = 0.f;
        for (int k = 0; k < T1; ++k) acc += Ash[k] * hp[(size_t)k * 2 * HD];
        sf[(size_t)bq * 2 * HD + d] = acc * inv;
    }
}

// state_semantic + val. grid 4, block 256.
__global__ __launch_bounds__(256) void val_kernel(
    const float* __restrict__ sf, const float* __restrict__ am,
    const float* __restrict__ vw, const float* __restrict__ vb,
    float* __restrict__ val)
{
    __shared__ float red[4];
    const int b = blockIdx.x, tid = threadIdx.x;
    float num = 0.f;
    for (int q = 0; q < NS2; ++q) num += am[b * NS2 + q];
    float acc = 0.f;
    for (int d = tid; d < 2 * HD; d += 256) {
        float s = 0.f;
        for (int q = 0; q < NS2; ++q) s += sf[((size_t)(b * NS2 + q)) * 2 * HD + d];
        acc += (s / num) * vw[d];
    }
#pragma unroll
    for (int off = 32; off; off >>= 1) acc += __shfl_xor(acc, off);
    if ((tid & 63) == 0) red[tid >> 6] = acc;
    __syncthreads();
    if (tid == 0) val[b] = red[0] + red[1] + red[2] + red[3] + vb[0];
}

// adv dot + mean-subtract + output. grid 4, block 256.
__global__ __launch_bounds__(256) void final_kernel(
    const float* __restrict__ Tb,   // [3][256][768]
    const float* __restrict__ act,  // [4][64][768]
    const float* __restrict__ bias, // [3]
    const float* __restrict__ val,  // [4]
    float* __restrict__ out)        // [256][3]
{
    __shared__ float adv[192];
    __shared__ float red[4];
    const int b = blockIdx.x, tid = threadIdx.x;
    const int lane = tid & 63, wid = tid >> 6;

    for (int idx = wid; idx < 192; idx += 4) {
        const int q = idx / 3, l = idx - q * 3;
        const float* tp = Tb + (size_t)l * T1 * HD + (size_t)(b * NS2 + q) * HD;
        const float* ap = act + (size_t)(b * NS2 + q) * HD;
        float s = 0.f;
#pragma unroll
        for (int i = 0; i < 12; ++i) {
            const int h = i * 64 + lane;
            s += tp[h] * ap[h];
        }
#pragma unroll
        for (int off = 32; off; off >>= 1) s += __shfl_xor(s, off);
        if (lane == 0) adv[idx] = s + bias[l];
    }
    __syncthreads();
    float part = (tid < 192) ? adv[tid] : 0.f;
#pragma unroll
    for (int off = 32; off; off >>= 1) part += __shfl_xor(part, off);
    if (lane == 0) red[wid] = part;
    __syncthreads();
    const float mean = (red[0] + red[1] + red[2] + red[3]) * (1.f / 192.f);
    const float vv = val[b];
    for (int idx = tid; idx < 192; idx += 256) {
        const int q = idx / 3, l = idx - q * 3;
        out[(size_t)(b * NS2 + q) * NL + l] = vv + adv[idx] - mean;
    }
}

// ---------------------------------------------------------------------------
extern "C" void kernel_launch(void* const* d_in, const int* in_sizes, int n_in,
                              void* d_out, int out_size, void* d_ws, size_t ws_size,
                              hipStream_t stream)
{
    const float* states = (const float*)d_in[0];
    const float* state_mask = (const float*)d_in[1];
    const float* actions = (const float*)d_in[2];
    const float* actions_mask = (const float*)d_in[3];
    const float* Wih0 = (const float*)d_in[4];   // [2,3072,768]
    const float* Whh0 = (const float*)d_in[5];   // [2,3072,768]
    const float* b0 = (const float*)d_in[6];     // [2,3072]
    const float* Wih12 = (const float*)d_in[7];  // [2,2,3072,1536]
    const float* Whh12 = (const float*)d_in[8];  // [2,2,3072,768]
    const float* b12 = (const float*)d_in[9];    // [2,2,3072]
    const float* aW1 = (const float*)d_in[10];   // [768,2304]
    const float* ab1 = (const float*)d_in[11];   // [768]
    const float* aW2 = (const float*)d_in[12];   // [1,768]
    const float* ab2 = (const float*)d_in[13];   // [1]
    const float* vW = (const float*)d_in[14];    // [1,1536]
    const float* vb = (const float*)d_in[15];    // [1]
    const float* wgt = (const float*)d_in[16];   // [3,768,1536]
    const float* bias = (const float*)d_in[17];  // [3]
    float* out = (float*)d_out;

    float* ws = (float*)d_ws;
    float* G = ws;                        // [2][4][256][3072] = 6291456 floats
    float* B1 = G + 6291456;              // H1, later H3  (1572864)
    float* B2 = B1 + 1572864;             // H2            (1572864)
    float* hg = B2 + 1572864;             // h ping-pong [2][2][768][4] = 12288
    unsigned* bar = (unsigned*)(hg + 12288);  // 1024 uints (ctr + gen)
    // after LSTM phase, G region is reused for attention temporaries:
    float* hq = G;                        // 256*768   = 196608
    float* hkb = G + 196608;              // 1024*768  = 786432
    float* sf = G + 983040;               // 256*1536  = 393216
    float* Tb = G + 1376256;              // 3*256*768 = 589824
    float* val = G + 1966080;             // 4

    const dim3 blk(256);
    const long long gstride = (long long)4 * T1 * G4;  // per-direction chunk in G

    // ---------------- layer 0 ----------------
    hipMemsetAsync(bar, 0, 4096, stream);
    gemm_f32<<<dim3(6144 / 64, 1024 / 64), blk, 0, stream>>>(
        states, HD, Wih0, HD, b0, G, HD, G4, gstride);
    lstm_scan<<<dim3(256), blk, 0, stream>>>(Whh0, G, B1, hg, bar, 0);
    // ---------------- layer 1 ----------------
    hipMemsetAsync(bar, 0, 4096, stream);
    gemm_f32<<<dim3(6144 / 64, 1024 / 64), blk, 0, stream>>>(
        B1, 2 * HD, Wih12, 2 * HD, b12, G, 2 * HD, G4, gstride);
    lstm_scan<<<dim3(256), blk, 0, stream>>>(Whh12, G, B2, hg, bar, 0);
    // ---------------- layer 2 ----------------
    hipMemsetAsync(bar, 0, 4096, stream);
    gemm_f32<<<dim3(6144 / 64, 1024 / 64), blk, 0, stream>>>(
        B2, 2 * HD, Wih12 + (size_t)6144 * 1536, 2 * HD, b12 + 6144, G, 2 * HD, G4, gstride);
    lstm_scan<<<dim3(256), blk, 0, stream>>>(
        Whh12 + (size_t)2 * G4 * HD, G, B1, hg, bar, 1);
    // ---------------- attention ----------------
    // hq = actions @ W1q^T + b1   (W1q = aW1[:, :768], row stride 2304)
    gemm_f32<<<dim3(768 / 64, 256 / 64), blk, 0, stream>>>(
        actions, HD, aW1, 2304, ab1, hq, HD, HD, 0);
    // hk = out @ W1k^T            (W1k = aW1[:, 768:2304], K = 1536)
    gemm_f32<<<dim3(768 / 64, 1024 / 64), blk, 0, stream>>>(
        B1, 2 * HD, aW1 + 768, 2304, nullptr, hkb, 2 * HD, HD, 0);
    attn_kernel<<<dim3(256), blk, 0, stream>>>(hq, hkb, aW2, ab2, actions_mask,
                                               state_mask, B1, sf);
    val_kernel<<<dim3(4), blk, 0, stream>>>(sf, actions_mask, vW, vb, val);
    // T_l = sf @ weight[l]^T
    for (int l = 0; l < NL; ++l) {
        gemm_f32<<<dim3(768 / 64, 256 / 64), blk, 0, stream>>>(
            sf, 2 * HD, wgt + (size_t)l * HD * 2 * HD, 2 * HD, nullptr,
            Tb + (size_t)l * T1 * HD, 2 * HD, HD, 0);
    }
    final_kernel<<<dim3(4), blk, 0, stream>>>(Tb, actions, bias, val, out);
}

// Round 7
// 3877.010 us; speedup vs baseline: 1.3617x; 1.1080x over previous
//
#include <hip/hip_runtime.h>

#define HD 768
#define G4 3072
#define T1 256
#define NS2 64
#define NL 3
#define NBLK_DIR 128   // blocks per direction in lstm_scan
#define UPB 6          // hidden units per block

__device__ __forceinline__ float sigf(float x) { return 1.0f / (1.0f + expf(-x)); }

__device__ __forceinline__ void fence_vm() {
    asm volatile("s_waitcnt vmcnt(0)" ::: "memory");
}

// ---------------------------------------------------------------------------
// Tiled f32 GEMM (small/medium): 64x64 tile, 4x4 acc (round-2 proven).
// grid: (N/64, M/64).
// ---------------------------------------------------------------------------
__global__ __launch_bounds__(256) void gemm_f32(
    const float* __restrict__ A, int lda,
    const float* __restrict__ W, int ldw,
    const float* __restrict__ bias,
    float* __restrict__ C,
    int K, int n_per_chunk, long long chunk_stride)
{
    __shared__ __align__(16) float As[16 * 64];
    __shared__ __align__(16) float Ws[16 * 64];
    const int tid = threadIdx.x;
    const int tx = tid & 15, ty = tid >> 4;
    const int n0 = blockIdx.x * 64, m0 = blockIdx.y * 64;
    const int lr = tid >> 2, lc = tid & 3;

    float acc[4][4] = {{0.f}};
    const float* Ap = A + (size_t)(m0 + lr) * lda + lc * 4;
    const float* Wp = W + (size_t)(n0 + lr) * ldw + lc * 4;

    for (int k0 = 0; k0 < K; k0 += 16) {
        float4 av = *(const float4*)(Ap + k0);
        float4 wv = *(const float4*)(Wp + k0);
        __syncthreads();
        As[(lc * 4 + 0) * 64 + lr] = av.x;
        As[(lc * 4 + 1) * 64 + lr] = av.y;
        As[(lc * 4 + 2) * 64 + lr] = av.z;
        As[(lc * 4 + 3) * 64 + lr] = av.w;
        Ws[(lc * 4 + 0) * 64 + lr] = wv.x;
        Ws[(lc * 4 + 1) * 64 + lr] = wv.y;
        Ws[(lc * 4 + 2) * 64 + lr] = wv.z;
        Ws[(lc * 4 + 3) * 64 + lr] = wv.w;
        __syncthreads();
#pragma unroll
        for (int k = 0; k < 16; ++k) {
            float4 a = *(const float4*)&As[k * 64 + ty * 4];
            float4 b = *(const float4*)&Ws[k * 64 + tx * 4];
            float aa[4] = {a.x, a.y, a.z, a.w};
            float bb[4] = {b.x, b.y, b.z, b.w};
#pragma unroll
            for (int i = 0; i < 4; ++i)
#pragma unroll
                for (int j = 0; j < 4; ++j) acc[i][j] += aa[i] * bb[j];
        }
    }

    const int jg = n0 + tx * 4;
    const int chunk = jg / n_per_chunk;
    const int jo = jg - chunk * n_per_chunk;
    float4 bv = make_float4(0.f, 0.f, 0.f, 0.f);
    if (bias) bv = *(const float4*)&bias[jg];
    float* Cb = C + (size_t)chunk * chunk_stride + jo;
#pragma unroll
    for (int i = 0; i < 4; ++i) {
        const int m = m0 + ty * 4 + i;
        float4 o;
        o.x = acc[i][0] + bv.x;
        o.y = acc[i][1] + bv.y;
        o.z = acc[i][2] + bv.z;
        o.w = acc[i][3] + bv.w;
        *(float4*)&Cb[(size_t)m * n_per_chunk] = o;
    }
}

// ---------------------------------------------------------------------------
// FMA-bound GEMM for the big ih-GEMMs: 128x64 tile, 256 threads, 8x4 acc.
// Per k: 3 ds_read_b128 (~36cy) feed 32 FMA (~64cy wave64) -> FMA-bound.
// grid: (N/64, M/128). Requires M%128==0, N%64==0, K%16==0.
// ---------------------------------------------------------------------------
__global__ __launch_bounds__(256) void gemm_f32_big(
    const float* __restrict__ A, int lda,
    const float* __restrict__ W, int ldw,
    const float* __restrict__ bias,
    float* __restrict__ C,
    int K, int n_per_chunk, long long chunk_stride)
{
    __shared__ __align__(16) float As[16 * 128];  // [k][m]
    __shared__ __align__(16) float Ws[16 * 64];   // [k][n]
    const int tid = threadIdx.x;
    const int tx = tid & 15, ty = tid >> 4;       // n-col group / m-row group
    const int n0 = blockIdx.x * 64, m0 = blockIdx.y * 128;
    const int ar = tid >> 1, ac = tid & 1;        // A: 2 thr/row, 8 cols each
    const int br = tid >> 2, bc = tid & 3;        // B: 4 thr/row, 4 cols each

    float acc[8][4] = {{0.f}};
    const float* Ap = A + (size_t)(m0 + ar) * lda + ac * 8;
    const float* Wp = W + (size_t)(n0 + br) * ldw + bc * 4;

    for (int k0 = 0; k0 < K; k0 += 16) {
        float4 a0 = *(const float4*)(Ap + k0);
        float4 a1 = *(const float4*)(Ap + k0 + 4);
        float4 wv = *(const float4*)(Wp + k0);
        __syncthreads();
        const int kb = ac * 8;
        As[(kb + 0) * 128 + ar] = a0.x;
        As[(kb + 1) * 128 + ar] = a0.y;
        As[(kb + 2) * 128 + ar] = a0.z;
        As[(kb + 3) * 128 + ar] = a0.w;
        As[(kb + 4) * 128 + ar] = a1.x;
        As[(kb + 5) * 128 + ar] = a1.y;
        As[(kb + 6) * 128 + ar] = a1.z;
        As[(kb + 7) * 128 + ar] = a1.w;
        Ws[(bc * 4 + 0) * 64 + br] = wv.x;
        Ws[(bc * 4 + 1) * 64 + br] = wv.y;
        Ws[(bc * 4 + 2) * 64 + br] = wv.z;
        Ws[(bc * 4 + 3) * 64 + br] = wv.w;
        __syncthreads();
#pragma unroll
        for (int k = 0; k < 16; ++k) {
            float4 xa = *(const float4*)&As[k * 128 + ty * 8];
            float4 xb = *(const float4*)&As[k * 128 + ty * 8 + 4];
            float4 yv = *(const float4*)&Ws[k * 64 + tx * 4];
            float av[8] = {xa.x, xa.y, xa.z, xa.w, xb.x, xb.y, xb.z, xb.w};
            float bv[4] = {yv.x, yv.y, yv.z, yv.w};
#pragma unroll
            for (int i = 0; i < 8; ++i)
#pragma unroll
                for (int j = 0; j < 4; ++j) acc[i][j] += av[i] * bv[j];
        }
    }

    const int jg = n0 + tx * 4;
    const int chunk = jg / n_per_chunk;
    const int jo = jg - chunk * n_per_chunk;
    float4 bv4 = make_float4(0.f, 0.f, 0.f, 0.f);
    if (bias) bv4 = *(const float4*)&bias[jg];
    float* Cb = C + (size_t)chunk * chunk_stride + jo;
#pragma unroll
    for (int i = 0; i < 8; ++i) {
        const int m = m0 + ty * 8 + i;
        float4 o;
        o.x = acc[i][0] + bv4.x;
        o.y = acc[i][1] + bv4.y;
        o.z = acc[i][2] + bv4.z;
        o.w = acc[i][3] + bv4.w;
        *(float4*)&Cb[(size_t)m * n_per_chunk] = o;
    }
}

// ---------------------------------------------------------------------------
// Persistent bidirectional LSTM scan for one layer (round-6 measured-best,
// FROZEN). grid 256 blocks: dir = bid&1, 128 blocks/dir, 6 units per block.
// Whh rows in REGISTERS. Relaxed striped-counter barrier, master polls 8
// stripes, publishes gen; others spin on gen. h via agent-scope relaxed
// atomics. Hout (HBM) stored AFTER fence+arrival. Counters zeroed per layer.
//   bar: ctr[dir][8] at bar + dir*256 + i*32 ; gen[dir] at bar + 512 + dir*32
// ---------------------------------------------------------------------------
__global__ __launch_bounds__(256) void lstm_scan(
    const float* __restrict__ Whh,
    const float* __restrict__ G,
    float* __restrict__ Hout,
    float* __restrict__ hglob,
    unsigned* __restrict__ bar,
    int last)
{
    // padded LDS: unit k's 4 batch values in float4 slot 5*(k>>2)+(k&3)
    __shared__ __align__(16) float4 hs[960];
    __shared__ float gl[24 * 4];
    __shared__ float cst[24];
    const int tid = threadIdx.x;
    const int bid = blockIdx.x;
    const int dir = bid & 1;
    const int blkd = bid >> 1;
    const int u0 = blkd * UPB;

    const int ks = tid & 15, jp = tid >> 4;   // 16 k-slices x 16 row-pairs (12 used)
    const bool act = (jp < 12);
    const bool kz = act && (ks == 0);

    // ---- load this block's Whh rows into registers (once per layer) ----
    const int r0 = 2 * jp, r1 = 2 * jp + 1;
    const int j0 = (r0 / 6) * HD + u0 + (r0 % 6);
    const int j1 = (r1 / 6) * HD + u0 + (r1 % 6);
    float4 w0[12], w1[12];
    if (act) {
        const float4* W4 = (const float4*)Whh + (size_t)dir * G4 * 192;
#pragma unroll
        for (int i = 0; i < 12; ++i) {
            w0[i] = W4[(size_t)j0 * 192 + i * 16 + ks];
            w1[i] = W4[(size_t)j1 * 192 + i * 16 + ks];
        }
    }
    if (tid < 24) cst[tid] = 0.f;

    unsigned* ctr = bar + dir * 256;
    unsigned* genp = bar + 512 + dir * 32;
    const size_t gdb = (size_t)dir * 4 * T1 * G4;
    const size_t bstr = (size_t)T1 * G4;
    float* hsf = (float*)hs;

    for (int s = 0; s < T1; ++s) {
        const int t = dir ? (T1 - 1 - s) : s;

        // prefetch ih-gate values (independent of h; hides under staging/matvec)
        float gA[4], gB[4];
        if (kz) {
            const float* Gt = G + gdb + (size_t)t * G4;
#pragma unroll
            for (int b = 0; b < 4; ++b) {
                gA[b] = Gt[(size_t)b * bstr + j0];
                gB[b] = Gt[(size_t)b * bstr + j1];
            }
        }

        // ---- stage h_t into LDS ----
        if (s == 0) {
#pragma unroll
            for (int r = 0; r < 3; ++r) {
                const int k = tid + 256 * r;
                hs[5 * (k >> 2) + (k & 3)] = make_float4(0.f, 0.f, 0.f, 0.f);
            }
        } else {
            const float* hp = hglob + ((size_t)((s & 1) * 2 + dir)) * HD * 4;
            float hv[12];
#pragma unroll
            for (int r = 0; r < 12; ++r)
                hv[r] = __hip_atomic_load(hp + tid + 256 * r, __ATOMIC_RELAXED,
                                          __HIP_MEMORY_SCOPE_AGENT);
#pragma unroll
            for (int r = 0; r < 12; ++r) {
                const int i = tid + 256 * r;
                const int k = i >> 2, b = i & 3;
                hsf[(5 * (k >> 2) + (k & 3)) * 4 + b] = hv[r];
            }
        }
        __syncthreads();

        // ---- matvec: 2 rows x 48 k x 4 batch per thread ----
        if (act) {
            float4 a0 = make_float4(0.f, 0.f, 0.f, 0.f);
            float4 a1 = make_float4(0.f, 0.f, 0.f, 0.f);
#pragma unroll
            for (int i = 0; i < 12; ++i) {
                const int pb = 5 * (i * 16 + ks);
                const float4 h0 = hs[pb + 0];
                const float4 h1 = hs[pb + 1];
                const float4 h2 = hs[pb + 2];
                const float4 h3 = hs[pb + 3];
                const float4 wa = w0[i];
                const float4 wb = w1[i];
                a0.x += wa.x * h0.x; a0.y += wa.x * h0.y; a0.z += wa.x * h0.z; a0.w += wa.x * h0.w;
                a0.x += wa.y * h1.x; a0.y += wa.y * h1.y; a0.z += wa.y * h1.z; a0.w += wa.y * h1.w;
                a0.x += wa.z * h2.x; a0.y += wa.z * h2.y; a0.z += wa.z * h2.z; a0.w += wa.z * h2.w;
                a0.x += wa.w * h3.x; a0.y += wa.w * h3.y; a0.z += wa.w * h3.z; a0.w += wa.w * h3.w;
                a1.x += wb.x * h0.x; a1.y += wb.x * h0.y; a1.z += wb.x * h0.z; a1.w += wb.x * h0.w;
                a1.x += wb.y * h1.x; a1.y += wb.y * h1.y; a1.z += wb.y * h1.z; a1.w += wb.y * h1.w;
                a1.x += wb.z * h2.x; a1.y += wb.z * h2.y; a1.z += wb.z * h2.z; a1.w += wb.z * h2.w;
                a1.x += wb.w * h3.x; a1.y += wb.w * h3.y; a1.z += wb.w * h3.z; a1.w += wb.w * h3.w;
            }
#pragma unroll
            for (int off = 1; off < 16; off <<= 1) {
                a0.x += __shfl_xor(a0.x, off);
                a0.y += __shfl_xor(a0.y, off);
                a0.z += __shfl_xor(a0.z, off);
                a0.w += __shfl_xor(a0.w, off);
                a1.x += __shfl_xor(a1.x, off);
                a1.y += __shfl_xor(a1.y, off);
                a1.z += __shfl_xor(a1.z, off);
                a1.w += __shfl_xor(a1.w, off);
            }
            if (ks == 0) {
                gl[r0 * 4 + 0] = a0.x + gA[0];
                gl[r0 * 4 + 1] = a0.y + gA[1];
                gl[r0 * 4 + 2] = a0.z + gA[2];
                gl[r0 * 4 + 3] = a0.w + gA[3];
                gl[r1 * 4 + 0] = a1.x + gB[0];
                gl[r1 * 4 + 1] = a1.y + gB[1];
                gl[r1 * 4 + 2] = a1.z + gB[2];
                gl[r1 * 4 + 3] = a1.w + gB[3];
            }
        }
        __syncthreads();

        // ---- cell update: 6 units x 4 batch; publish h at agent scope ----
        float hval = 0.f;
        if (tid < 24) {
            const int ui = tid >> 2, b = tid & 3;
            const float gi = gl[(0 * 6 + ui) * 4 + b];
            const float gf = gl[(1 * 6 + ui) * 4 + b];
            const float gg = gl[(2 * 6 + ui) * 4 + b];
            const float go = gl[(3 * 6 + ui) * 4 + b];
            const float c = sigf(gf) * cst[tid] + sigf(gi) * tanhf(gg);
            hval = sigf(go) * tanhf(c);
            cst[tid] = c;
            __hip_atomic_store(
                &hglob[(((size_t)(((s + 1) & 1) * 2 + dir)) * HD + (u0 + ui)) * 4 + b],
                hval, __ATOMIC_RELAXED, __HIP_MEMORY_SCOPE_AGENT);
        }
        // wave 0 drains its h stores, then thread 0 announces arrival
        if (tid < 64) fence_vm();
        if (s < T1 - 1 && tid == 0) {
            __hip_atomic_fetch_add(&ctr[(blkd & 7) * 32], 1u, __ATOMIC_RELAXED,
                                   __HIP_MEMORY_SCOPE_AGENT);
        }
        // Hout store (HBM) AFTER the fence+arrival: off the publisher chain
        if (tid < 24) {
            const int ui = tid >> 2, b = tid & 3;
            Hout[((size_t)b * T1 + t) * (2 * HD) + dir * HD + (u0 + ui)] =
                last ? tanhf(hval) : hval;
        }

        // ---- wait: master polls stripes, publishes gen; others spin ----
        if (s < T1 - 1) {
            if (tid == 0) {
                const unsigned tgt = (unsigned)(NBLK_DIR * (s + 1));
                if (blkd == 0) {
                    for (;;) {
                        unsigned sum = 0;
#pragma unroll
                        for (int i = 0; i < 8; ++i)
                            sum += __hip_atomic_load(&ctr[i * 32], __ATOMIC_RELAXED,
                                                     __HIP_MEMORY_SCOPE_AGENT);
                        if (sum >= tgt) break;
                    }
                    __hip_atomic_store(genp, (unsigned)(s + 1), __ATOMIC_RELAXED,
                                       __HIP_MEMORY_SCOPE_AGENT);
                } else {
                    while (__hip_atomic_load(genp, __ATOMIC_RELAXED,
                                             __HIP_MEMORY_SCOPE_AGENT) <
                           (unsigned)(s + 1)) {}
                }
            }
            __syncthreads();
        }
    }
}

// ---------------------------------------------------------------------------
// Attention: per (b,q) block. hq includes attn_b1. hk: [4*256][768].
// ---------------------------------------------------------------------------
__global__ __launch_bounds__(256) void attn_kernel(
    const float* __restrict__ hq,
    const float* __restrict__ hk,
    const float* __restrict__ w2p,
    const float* __restrict__ b2p,
    const float* __restrict__ am,
    const float* __restrict__ sm,
    const float* __restrict__ H3,
    float* __restrict__ sf)
{
    __shared__ float hql[HD];
    __shared__ float w2[HD];
    __shared__ float Ash[T1];
    __shared__ float red[1];
    const int tid = threadIdx.x;
    const int bq = blockIdx.x;
    const int b = bq >> 6;

    for (int e = tid; e < HD; e += 256) {
        hql[e] = hq[(size_t)bq * HD + e];
        w2[e] = w2p[e];
    }
    __syncthreads();

    const int lane = tid & 63, wid = tid >> 6;
    const float amv = am[bq];
    const float b2 = b2p[0];
    for (int k = wid; k < T1; k += 4) {
        const float* hkp = hk + ((size_t)b * T1 + k) * HD;
        float s = 0.f;
#pragma unroll
        for (int i = 0; i < 12; ++i) {
            const int e = i * 64 + lane;
            float v = hql[e] + hkp[e];
            v = v > 0.f ? v : 0.f;
            s += v * w2[e];
        }
#pragma unroll
        for (int off = 32; off; off >>= 1) s += __shfl_xor(s, off);
        if (lane == 0) {
            const float m = amv * sm[b * T1 + k];
            Ash[k] = (m == 0.f) ? 0.f : expf(s + b2);
        }
    }
    __syncthreads();

    if (tid < 64) {
        float p = Ash[tid] + Ash[tid + 64] + Ash[tid + 128] + Ash[tid + 192];
#pragma unroll
        for (int off = 32; off; off >>= 1) p += __shfl_xor(p, off);
        if (tid == 0) red[0] = fmaxf(p, 2e-15f);
    }
    __syncthreads();
    const float inv = 1.f / red[0];

    for (int d = tid; d < 2 * HD; d += 256) {
        const float* hp = H3 + (size_t)b * T1 * 2 * HD + d;
        float acc = 0.f;
        for (int k = 0; k < T1; ++k) acc += Ash[k] * hp[(size_t)k * 2 * HD];
        sf[(size_t)bq * 2 * HD + d] = acc * inv;
    }
}

// state_semantic + val. grid 4, block 256.
__global__ __launch_bounds__(256) void val_kernel(
    const float* __restrict__ sf, const float* __restrict__ am,
    const float* __restrict__ vw, const float* __restrict__ vb,
    float* __restrict__ val)
{
    __shared__ float red[4];
    const int b = blockIdx.x, tid = threadIdx.x;
    float num = 0.f;
    for (int q = 0; q < NS2; ++q) num += am[b * NS2 + q];
    float acc = 0.f;
    for (int d = tid; d < 2 * HD; d += 256) {
        float s = 0.f;
        for (int q = 0; q < NS2; ++q) s += sf[((size_t)(b * NS2 + q)) * 2 * HD + d];
        acc += (s / num) * vw[d];
    }
#pragma unroll
    for (int off = 32; off; off >>= 1) acc += __shfl_xor(acc, off);
    if ((tid & 63) == 0) red[tid >> 6] = acc;
    __syncthreads();
    if (tid == 0) val[b] = red[0] + red[1] + red[2] + red[3] + vb[0];
}

// adv dot + mean-subtract + output. grid 4, block 256.
__global__ __launch_bounds__(256) void final_kernel(
    const float* __restrict__ Tb,   // [3][256][768]
    const float* __restrict__ act,  // [4][64][768]
    const float* __restrict__ bias, // [3]
    const float* __restrict__ val,  // [4]
    float* __restrict__ out)        // [256][3]
{
    __shared__ float adv[192];
    __shared__ float red[4];
    const int b = blockIdx.x, tid = threadIdx.x;
    const int lane = tid & 63, wid = tid >> 6;

    for (int idx = wid; idx < 192; idx += 4) {
        const int q = idx / 3, l = idx - q * 3;
        const float* tp = Tb + (size_t)l * T1 * HD + (size_t)(b * NS2 + q) * HD;
        const float* ap = act + (size_t)(b * NS2 + q) * HD;
        float s = 0.f;
#pragma unroll
        for (int i = 0; i < 12; ++i) {
            const int h = i * 64 + lane;
            s += tp[h] * ap[h];
        }
#pragma unroll
        for (int off = 32; off; off >>= 1) s += __shfl_xor(s, off);
        if (lane == 0) adv[idx] = s + bias[l];
    }
    __syncthreads();
    float part = (tid < 192) ? adv[tid] : 0.f;
#pragma unroll
    for (int off = 32; off; off >>= 1) part += __shfl_xor(part, off);
    if (lane == 0) red[wid] = part;
    __syncthreads();
    const float mean = (red[0] + red[1] + red[2] + red[3]) * (1.f / 192.f);
    const float vv = val[b];
    for (int idx = tid; idx < 192; idx += 256) {
        const int q = idx / 3, l = idx - q * 3;
        out[(size_t)(b * NS2 + q) * NL + l] = vv + adv[idx] - mean;
    }
}

// ---------------------------------------------------------------------------
extern "C" void kernel_launch(void* const* d_in, const int* in_sizes, int n_in,
                              void* d_out, int out_size, void* d_ws, size_t ws_size,
                              hipStream_t stream)
{
    const float* states = (const float*)d_in[0];
    const float* state_mask = (const float*)d_in[1];
    const float* actions = (const float*)d_in[2];
    const float* actions_mask = (const float*)d_in[3];
    const float* Wih0 = (const float*)d_in[4];   // [2,3072,768]
    const float* Whh0 = (const float*)d_in[5];   // [2,3072,768]
    const float* b0 = (const float*)d_in[6];     // [2,3072]
    const float* Wih12 = (const float*)d_in[7];  // [2,2,3072,1536]
    const float* Whh12 = (const float*)d_in[8];  // [2,2,3072,768]
    const float* b12 = (const float*)d_in[9];    // [2,2,3072]
    const float* aW1 = (const float*)d_in[10];   // [768,2304]
    const float* ab1 = (const float*)d_in[11];   // [768]
    const float* aW2 = (const float*)d_in[12];   // [1,768]
    const float* ab2 = (const float*)d_in[13];   // [1]
    const float* vW = (const float*)d_in[14];    // [1,1536]
    const float* vb = (const float*)d_in[15];    // [1]
    const float* wgt = (const float*)d_in[16];   // [3,768,1536]
    const float* bias = (const float*)d_in[17];  // [3]
    float* out = (float*)d_out;

    float* ws = (float*)d_ws;
    float* G = ws;                        // [2][4][256][3072] = 6291456 floats
    float* B1 = G + 6291456;              // H1, later H3  (1572864)
    float* B2 = B1 + 1572864;             // H2            (1572864)
    float* hg = B2 + 1572864;             // h ping-pong [2][2][768][4] = 12288
    unsigned* bar = (unsigned*)(hg + 12288);  // 1024 uints (ctr + gen)
    // after LSTM phase, G region is reused for attention temporaries:
    float* hq = G;                        // 256*768   = 196608
    float* hkb = G + 196608;              // 1024*768  = 786432
    float* sf = G + 983040;               // 256*1536  = 393216
    float* Tb = G + 1376256;              // 3*256*768 = 589824
    float* val = G + 1966080;             // 4

    const dim3 blk(256);
    const long long gstride = (long long)4 * T1 * G4;  // per-direction chunk in G

    // ---------------- layer 0 ----------------
    hipMemsetAsync(bar, 0, 4096, stream);
    gemm_f32_big<<<dim3(6144 / 64, 1024 / 128), blk, 0, stream>>>(
        states, HD, Wih0, HD, b0, G, HD, G4, gstride);
    lstm_scan<<<dim3(256), blk, 0, stream>>>(Whh0, G, B1, hg, bar, 0);
    // ---------------- layer 1 ----------------
    hipMemsetAsync(bar, 0, 4096, stream);
    gemm_f32_big<<<dim3(6144 / 64, 1024 / 128), blk, 0, stream>>>(
        B1, 2 * HD, Wih12, 2 * HD, b12, G, 2 * HD, G4, gstride);
    lstm_scan<<<dim3(256), blk, 0, stream>>>(Whh12, G, B2, hg, bar, 0);
    // ---------------- layer 2 ----------------
    hipMemsetAsync(bar, 0, 4096, stream);
    gemm_f32_big<<<dim3(6144 / 64, 1024 / 128), blk, 0, stream>>>(
        B2, 2 * HD, Wih12 + (size_t)6144 * 1536, 2 * HD, b12 + 6144, G, 2 * HD, G4, gstride);
    lstm_scan<<<dim3(256), blk, 0, stream>>>(
        Whh12 + (size_t)2 * G4 * HD, G, B1, hg, bar, 1);
    // ---------------- attention ----------------
    // hq = actions @ W1q^T + b1   (W1q = aW1[:, :768], row stride 2304)
    gemm_f32<<<dim3(768 / 64, 256 / 64), blk, 0, stream>>>(
        actions, HD, aW1, 2304, ab1, hq, HD, HD, 0);
    // hk = out @ W1k^T            (W1k = aW1[:, 768:2304], K = 1536)
    gemm_f32<<<dim3(768 / 64, 1024 / 64), blk, 0, stream>>>(
        B1, 2 * HD, aW1 + 768, 2304, nullptr, hkb, 2 * HD, HD, 0);
    attn_kernel<<<dim3(256), blk, 0, stream>>>(hq, hkb, aW2, ab2, actions_mask,
                                               state_mask, B1, sf);
    val_kernel<<<dim3(4), blk, 0, stream>>>(sf, actions_mask, vW, vb, val);
    // T = sf @ wgt^T, all 3 labels in ONE launch (wgt rows contiguous: 2304x1536)
    gemm_f32<<<dim3(2304 / 64, 256 / 64), blk, 0, stream>>>(
        sf, 2 * HD, wgt, 2 * HD, nullptr, Tb, 2 * HD, HD, (long long)T1 * HD);
    final_kernel<<<dim3(4), blk, 0, stream>>>(Tb, actions, bias, val, out);
}